// Round 8
// baseline (132.578 us; speedup 1.0000x reference)
//
#include <hip/hip_runtime.h>
#include <math.h>

namespace {

typedef short short8 __attribute__((ext_vector_type(8)));
typedef float floatx4 __attribute__((ext_vector_type(4)));
typedef unsigned int uint32;
typedef unsigned short u16;
typedef unsigned long long u64;

constexpr int S = 256, B = 32, D = 512, H = 512;
constexpr int BH = B * H;        // 16384
constexpr int M1 = S * B;        // 8192
constexpr int WN = H * D;        // 262144
constexpr int SBH = S * BH;      // 4194304 (== B*D*S)

// LDS tiles: rows of exactly 64 bf16 (128B), 16B slot XOR-swizzled by row&7.
__device__ __forceinline__ int swz(int row, int col8) {
  return row * 64 + (col8 ^ ((row & 7) << 3));
}

__device__ __forceinline__ uint32 f2bf(float f) {
  uint32 x = __float_as_uint(f);
  return (x + 0x7fffu + ((x >> 16) & 1u)) >> 16;  // RNE
}

__device__ __forceinline__ float fast_sigmoid(float x) {
  float e = __expf(-x);
  return __builtin_amdgcn_rcpf(1.0f + e);
}
__device__ __forceinline__ float fast_tanh(float x) {
  float e = __expf(-2.0f * x);
  return fmaf(2.0f, __builtin_amdgcn_rcpf(1.0f + e), -1.0f);
}

// ---------------------------------------------------------------------------
// Convert weights to bf16.
// ---------------------------------------------------------------------------
__global__ __launch_bounds__(256) void convert_w(
    const float* __restrict__ wmz, const float* __restrict__ wmf,
    u16* __restrict__ wmzb, u16* __restrict__ wmfb) {
  int i = (blockIdx.x * 256 + threadIdx.x) * 8;
  const float* src;
  u16* dst;
  int off;
  if (i < WN) {
    src = wmz; dst = wmzb; off = i;
  } else {
    src = wmf; dst = wmfb; off = i - WN;
  }
  float4 a = *(const float4*)&src[off];
  float4 b = *(const float4*)&src[off + 4];
  uint4 o;
  o.x = f2bf(a.x) | (f2bf(a.y) << 16);
  o.y = f2bf(a.z) | (f2bf(a.w) << 16);
  o.z = f2bf(b.x) | (f2bf(b.y) << 16);
  o.w = f2bf(b.z) | (f2bf(b.w) << 16);
  *(uint4*)&dst[off] = o;
}

// ---------------------------------------------------------------------------
// Transpose+convert: x (S,B,D) f32  ->  XT [b][d][t] bf16.
// ---------------------------------------------------------------------------
__global__ __launch_bounds__(256) void xpose_kernel(
    const float* __restrict__ x, u16* __restrict__ XT) {
  __shared__ float lds[64][65];
  const int s0 = blockIdx.x * 64;
  const int d0 = blockIdx.y * 64;
  const int b = blockIdx.z;
  const int r = threadIdx.x >> 4;         // 0..15
  const int c4 = (threadIdx.x & 15) * 4;  // 0..60
#pragma unroll
  for (int p = 0; p < 4; ++p) {
    const int rr = r + p * 16;
    float4 v = *(const float4*)&x[(size_t)(s0 + rr) * (B * D) +
                                  (size_t)b * D + d0 + c4];
    lds[c4 + 0][rr] = v.x;
    lds[c4 + 1][rr] = v.y;
    lds[c4 + 2][rr] = v.z;
    lds[c4 + 3][rr] = v.w;
  }
  __syncthreads();
#pragma unroll
  for (int p = 0; p < 4; ++p) {
    const int dr = r + p * 16;
    const float v0 = lds[dr][c4 + 0];
    const float v1 = lds[dr][c4 + 1];
    const float v2 = lds[dr][c4 + 2];
    const float v3 = lds[dr][c4 + 3];
    u64 o = (u64)f2bf(v0) | ((u64)f2bf(v1) << 16) | ((u64)f2bf(v2) << 32) |
            ((u64)f2bf(v3) << 48);
    *(u64*)&XT[((size_t)b * D + d0 + dr) * S + s0 + c4] = o;
  }
}

// ---------------------------------------------------------------------------
// Proj GEMM (MFMA): pre[m][h] = sum_d x[m][d]*wm[h][d], dual-B, out float2.
// BM=128, BN=64, BK=64. Swizzled LDS. x f32->bf16 in-register. (unchanged)
// ---------------------------------------------------------------------------
__global__ __launch_bounds__(256) void proj_gemm(
    const float* __restrict__ x, const u16* __restrict__ wmzb,
    const u16* __restrict__ wmfb, float2* __restrict__ pzf) {
  __shared__ u16 As[128 * 64];
  __shared__ u16 Bzs[64 * 64];
  __shared__ u16 Bfs[64 * 64];
  const int tid = threadIdx.x;
  const int m0 = blockIdx.x * 128;
  const int n0 = blockIdx.y * 64;
  const int w = tid >> 6, l = tid & 63;
  const int lr = l & 15, lg = l >> 4;
  floatx4 accz[2][4], accf[2][4];
#pragma unroll
  for (int m = 0; m < 2; ++m)
#pragma unroll
    for (int n = 0; n < 4; ++n) {
      accz[m][n] = 0;
      accf[m][n] = 0;
    }
  const int sr = tid >> 3;         // 0..31
  const int sc = (tid & 7) * 8;    // 0..56
  for (int k0 = 0; k0 < D; k0 += 64) {
    __syncthreads();
#pragma unroll
    for (int p = 0; p < 4; ++p) {
      const int r = sr + 32 * p;
      const float* xp = &x[(size_t)(m0 + r) * D + k0 + sc];
      float4 a = *(const float4*)xp;
      float4 b = *(const float4*)(xp + 4);
      uint4 o;
      o.x = f2bf(a.x) | (f2bf(a.y) << 16);
      o.y = f2bf(a.z) | (f2bf(a.w) << 16);
      o.z = f2bf(b.x) | (f2bf(b.y) << 16);
      o.w = f2bf(b.z) | (f2bf(b.w) << 16);
      *(uint4*)&As[swz(r, sc)] = o;
    }
#pragma unroll
    for (int p = 0; p < 2; ++p) {
      const int r = sr + 32 * p;
      *(short8*)&Bzs[swz(r, sc)] =
          *(const short8*)&wmzb[(size_t)(n0 + r) * D + k0 + sc];
      *(short8*)&Bfs[swz(r, sc)] =
          *(const short8*)&wmfb[(size_t)(n0 + r) * D + k0 + sc];
    }
    __syncthreads();
#pragma unroll
    for (int kk = 0; kk < 2; ++kk) {
      const int kb = kk * 32 + lg * 8;
      short8 a0 = *(const short8*)&As[swz(32 * w + lr, kb)];
      short8 a1 = *(const short8*)&As[swz(32 * w + 16 + lr, kb)];
#pragma unroll
      for (int n = 0; n < 4; ++n) {
        short8 bz = *(const short8*)&Bzs[swz(16 * n + lr, kb)];
        short8 bf = *(const short8*)&Bfs[swz(16 * n + lr, kb)];
        accz[0][n] = __builtin_amdgcn_mfma_f32_16x16x32_bf16(a0, bz, accz[0][n], 0, 0, 0);
        accz[1][n] = __builtin_amdgcn_mfma_f32_16x16x32_bf16(a1, bz, accz[1][n], 0, 0, 0);
        accf[0][n] = __builtin_amdgcn_mfma_f32_16x16x32_bf16(a0, bf, accf[0][n], 0, 0, 0);
        accf[1][n] = __builtin_amdgcn_mfma_f32_16x16x32_bf16(a1, bf, accf[1][n], 0, 0, 0);
      }
    }
  }
#pragma unroll
  for (int m = 0; m < 2; ++m)
#pragma unroll
    for (int n = 0; n < 4; ++n)
#pragma unroll
      for (int j = 0; j < 4; ++j) {
        int row = m0 + 32 * w + 16 * m + lg * 4 + j;
        int col = n0 + 16 * n + lr;
        pzf[(size_t)row * H + col] = make_float2(accz[m][n][j], accf[m][n][j]);
      }
}

// ---------------------------------------------------------------------------
// Scan forward (unchanged).
// ---------------------------------------------------------------------------
#define STEP_BODY(J)                                                       \
    const float z = fast_tanh(fmaf(wvz, cell, pzv));                       \
    const float f = fast_sigmoid(fmaf(wvf, cell, pfv));                    \
    const float zf = (1.0f - f) * (1.0f - z * z);                          \
    const float fz = (cell - z) * (1.0f - f) * f;                          \
    const float common = f + zf * wvz + fz * wvf;                          \
    wz = fmaf(common, wz, cell * zf);                                      \
    wf = fmaf(common, wf, cell * fz);                                      \
    bz = fmaf(common, bz, zf);                                             \
    bf = fmaf(common, bf, fz);                                             \
    cell = fmaf(f, cell - z, z);                                           \
    const size_t ti = (size_t)(t0 + (J)) * BH;                             \
    cp[ti] = cell;                                                         \
    pz[ti] = make_float2(                                                  \
        __uint_as_float(f2bf(zf) | (f2bf(fz) << 16)), common);

#define STEP_L(J, Q)                                                       \
  {                                                                        \
    const float pzv = Q.x + bsz, pfv = Q.y + bsf;                          \
    Q = pz[(size_t)(t0 + 16 + (J)) * BH];                                  \
    STEP_BODY(J)                                                           \
  }

#define STEP_N(J, Q)                                                       \
  {                                                                        \
    const float pzv = Q.x + bsz, pfv = Q.y + bsf;                          \
    STEP_BODY(J)                                                           \
  }

__global__ __launch_bounds__(64, 1) void scan_fwd(
    const float* __restrict__ hidden_prev, const float* __restrict__ wz0,
    const float* __restrict__ wf0, const float* __restrict__ bz0,
    const float* __restrict__ bf0, const float* __restrict__ wvz_,
    const float* __restrict__ wvf_, const float* __restrict__ bsz_,
    const float* __restrict__ bsf_, float2* pzf_,
    float* __restrict__ out_cells, float* __restrict__ out_newcell,
    float* __restrict__ out_wzn, float* __restrict__ out_wfn,
    float* __restrict__ out_bzn, float* __restrict__ out_bfn) {
  const int bh = blockIdx.x * 64 + threadIdx.x;
  const int h = bh & (H - 1);
  float cell = hidden_prev[bh];
  float wz = wz0[bh], wf = wf0[bh], bz = bz0[bh], bf = bf0[bh];
  const float wvz = wvz_[h], wvf = wvf_[h], bsz = bsz_[h], bsf = bsf_[h];
  float2* pz = pzf_ + bh;
  float* cp = out_cells + bh;

  float2 q0 = pz[(size_t)0 * BH], q1 = pz[(size_t)1 * BH];
  float2 q2 = pz[(size_t)2 * BH], q3 = pz[(size_t)3 * BH];
  float2 q4 = pz[(size_t)4 * BH], q5 = pz[(size_t)5 * BH];
  float2 q6 = pz[(size_t)6 * BH], q7 = pz[(size_t)7 * BH];
  float2 q8 = pz[(size_t)8 * BH], q9 = pz[(size_t)9 * BH];
  float2 q10 = pz[(size_t)10 * BH], q11 = pz[(size_t)11 * BH];
  float2 q12 = pz[(size_t)12 * BH], q13 = pz[(size_t)13 * BH];
  float2 q14 = pz[(size_t)14 * BH], q15 = pz[(size_t)15 * BH];

  for (int t0 = 0; t0 < S - 16; t0 += 16) {
    STEP_L(0, q0)  STEP_L(1, q1)  STEP_L(2, q2)  STEP_L(3, q3)
    STEP_L(4, q4)  STEP_L(5, q5)  STEP_L(6, q6)  STEP_L(7, q7)
    STEP_L(8, q8)  STEP_L(9, q9)  STEP_L(10, q10) STEP_L(11, q11)
    STEP_L(12, q12) STEP_L(13, q13) STEP_L(14, q14) STEP_L(15, q15)
  }
  {
    const int t0 = S - 16;
    STEP_N(0, q0)  STEP_N(1, q1)  STEP_N(2, q2)  STEP_N(3, q3)
    STEP_N(4, q4)  STEP_N(5, q5)  STEP_N(6, q6)  STEP_N(7, q7)
    STEP_N(8, q8)  STEP_N(9, q9)  STEP_N(10, q10) STEP_N(11, q11)
    STEP_N(12, q12) STEP_N(13, q13) STEP_N(14, q14) STEP_N(15, q15)
  }
  out_newcell[bh] = cell;
  out_wzn[bh] = wz;
  out_wfn[bh] = wf;
  out_bzn[bh] = bz;
  out_bfn[bh] = bf;
}

// ---------------------------------------------------------------------------
// Suffix products + transpose to AzT/AfT [b][h][t] bf16. (unchanged)
// ---------------------------------------------------------------------------
__global__ __launch_bounds__(1024) void suffix_kernel(
    const float2* __restrict__ pzfc, u16* __restrict__ AzT,
    u16* __restrict__ AfT, float* __restrict__ P0_out) {
  __shared__ float prods[16][65];
  __shared__ uint32 tl[S * 65];   // [t][bh_l padded]
  const int bh_l = threadIdx.x & 63;
  const int c = threadIdx.x >> 6;
  const int bh = blockIdx.x * 64 + bh_l;
  const float2* p = pzfc + bh;
  float2 v[16];
#pragma unroll
  for (int i = 0; i < 16; ++i) v[i] = p[(size_t)(c * 16 + i) * BH];
  float L = 1.0f;
#pragma unroll
  for (int i = 0; i < 16; ++i) L *= v[i].y;
  prods[c][bh_l] = L;
  __syncthreads();
  float run = 1.0f;
#pragma unroll
  for (int cc = 1; cc < 16; ++cc)
    if (cc > c) run *= prods[cc][bh_l];
#pragma unroll
  for (int i = 15; i >= 0; --i) {
    const int t = c * 16 + i;
    const uint32 w32 = __float_as_uint(v[i].x);
    const float zf = __uint_as_float((w32 & 0xffffu) << 16);
    const float fz = __uint_as_float(w32 & 0xffff0000u);
    tl[t * 65 + bh_l] = f2bf(zf * run) | (f2bf(fz * run) << 16);
    run *= v[i].y;
  }
  if (c == 0) P0_out[bh] = run;
  __syncthreads();
  const size_t base = (size_t)blockIdx.x * 64 * S;
#pragma unroll
  for (int it = 0; it < 4; ++it) {
    const int qi = it * 1024 + threadIdx.x;  // 4096 quads
    const int r = qi >> 6;                   // chain row 0..63
    const int qt = (qi & 63) * 4;            // t 0..252
    const uint32 a0 = tl[(qt + 0) * 65 + r];
    const uint32 a1 = tl[(qt + 1) * 65 + r];
    const uint32 a2 = tl[(qt + 2) * 65 + r];
    const uint32 a3 = tl[(qt + 3) * 65 + r];
    u64 lo = (u64)(a0 & 0xffffu) | ((u64)(a1 & 0xffffu) << 16) |
             ((u64)(a2 & 0xffffu) << 32) | ((u64)(a3 & 0xffffu) << 48);
    u64 hi = (u64)(a0 >> 16) | ((u64)(a1 >> 16) << 16) |
             ((u64)(a2 >> 16) << 32) | ((u64)(a3 >> 16) << 48);
    *(u64*)&AzT[base + (size_t)r * S + qt] = lo;
    *(u64*)&AfT[base + (size_t)r * S + qt] = hi;
  }
}

// ---------------------------------------------------------------------------
// Out GEMM: Zn[b][h][d] = P0*Z0 + sum_t AzT[b][h][t]*XT[b][d][t]
// BM=128(h), BN=64(d), BK=64(t).
// Round-8: SINGLE 40KB LDS buffer + __launch_bounds__(256,4) -> 4 blocks/CU
// (16 waves/CU; round 7's 80KB dbuf capped at 2 blocks/CU = 15% occupancy,
// 2.6 TB/s). Reg-staged T14 pipeline kept: issue LOAD(t+1), COMPUTE(t) from
// LDS (hides the load latency), barrier, WRITE regs (vmcnt drain here),
// barrier. Cross-block overlap fills the drain stalls.
// ---------------------------------------------------------------------------
__global__ __launch_bounds__(256, 4) void out_gemm(
    const u16* __restrict__ AzT, const u16* __restrict__ AfT,
    const u16* __restrict__ XT, const float* __restrict__ P0,
    const float* __restrict__ Z0, const float* __restrict__ F0,
    float* __restrict__ Zn, float* __restrict__ Fn) {
  __shared__ u16 Azs[128 * 64];
  __shared__ u16 Afs[128 * 64];
  __shared__ u16 Xs[64 * 64];
  const int tid = threadIdx.x;
  const int h0 = blockIdx.x * 128;
  const int d0 = blockIdx.y * 64;
  const int b = blockIdx.z;
  const u16* Az = AzT + (size_t)b * H * S;
  const u16* Af = AfT + (size_t)b * H * S;
  const u16* Xb = XT + (size_t)b * D * S;
  const int w = tid >> 6, l = tid & 63;
  const int lr = l & 15, lg = l >> 4;
  floatx4 accz[2][4], accf[2][4];
#pragma unroll
  for (int m = 0; m < 2; ++m)
#pragma unroll
    for (int n = 0; n < 4; ++n) {
      accz[m][n] = 0;
      accf[m][n] = 0;
    }
  const int sr = tid >> 3;         // 0..31
  const int sc = (tid & 7) * 8;    // 0..56

  short8 rA[4], rF[4], rX[2];

#define OG_LOAD(T0)                                                        \
  {                                                                        \
    _Pragma("unroll") for (int p = 0; p < 4; ++p) {                        \
      const int r = sr + 32 * p;                                           \
      rA[p] = *(const short8*)&Az[(size_t)(h0 + r) * S + (T0) + sc];       \
      rF[p] = *(const short8*)&Af[(size_t)(h0 + r) * S + (T0) + sc];       \
    }                                                                      \
    _Pragma("unroll") for (int p = 0; p < 2; ++p) {                        \
      const int r = sr + 32 * p;                                           \
      rX[p] = *(const short8*)&Xb[(size_t)(d0 + r) * S + (T0) + sc];       \
    }                                                                      \
  }

#define OG_WRITE()                                                         \
  {                                                                        \
    _Pragma("unroll") for (int p = 0; p < 4; ++p) {                        \
      const int r = sr + 32 * p;                                           \
      *(short8*)&Azs[swz(r, sc)] = rA[p];                                  \
      *(short8*)&Afs[swz(r, sc)] = rF[p];                                  \
    }                                                                      \
    _Pragma("unroll") for (int p = 0; p < 2; ++p) {                        \
      const int r = sr + 32 * p;                                           \
      *(short8*)&Xs[swz(r, sc)] = rX[p];                                   \
    }                                                                      \
  }

#define OG_COMPUTE()                                                       \
  _Pragma("unroll") for (int kk = 0; kk < 2; ++kk) {                       \
    const int kb = kk * 32 + lg * 8;                                       \
    short8 az0 = *(const short8*)&Azs[swz(32 * w + lr, kb)];               \
    short8 az1 = *(const short8*)&Azs[swz(32 * w + 16 + lr, kb)];          \
    short8 af0 = *(const short8*)&Afs[swz(32 * w + lr, kb)];               \
    short8 af1 = *(const short8*)&Afs[swz(32 * w + 16 + lr, kb)];          \
    _Pragma("unroll") for (int n = 0; n < 4; ++n) {                        \
      short8 xf = *(const short8*)&Xs[swz(16 * n + lr, kb)];               \
      accz[0][n] = __builtin_amdgcn_mfma_f32_16x16x32_bf16(az0, xf, accz[0][n], 0, 0, 0); \
      accz[1][n] = __builtin_amdgcn_mfma_f32_16x16x32_bf16(az1, xf, accz[1][n], 0, 0, 0); \
      accf[0][n] = __builtin_amdgcn_mfma_f32_16x16x32_bf16(af0, xf, accf[0][n], 0, 0, 0); \
      accf[1][n] = __builtin_amdgcn_mfma_f32_16x16x32_bf16(af1, xf, accf[1][n], 0, 0, 0); \
    }                                                                      \
  }

  OG_LOAD(0)
  OG_WRITE()
  __syncthreads();
  OG_LOAD(64)
  OG_COMPUTE()
  __syncthreads();
  OG_WRITE()
  __syncthreads();
  OG_LOAD(128)
  OG_COMPUTE()
  __syncthreads();
  OG_WRITE()
  __syncthreads();
  OG_LOAD(192)
  OG_COMPUTE()
  __syncthreads();
  OG_WRITE()
  __syncthreads();
  OG_COMPUTE()

#pragma unroll
  for (int m = 0; m < 2; ++m)
#pragma unroll
    for (int j = 0; j < 4; ++j) {
      const int row = h0 + 32 * w + 16 * m + lg * 4 + j;
      const float p0 = P0[b * H + row];
#pragma unroll
      for (int n = 0; n < 4; ++n) {
        const int col = d0 + 16 * n + lr;
        const size_t idx = ((size_t)b * H + row) * D + col;
        Zn[idx] = fmaf(p0, Z0[idx], accz[m][n][j]);
        Fn[idx] = fmaf(p0, F0[idx], accf[m][n][j]);
      }
    }
#undef OG_LOAD
#undef OG_WRITE
#undef OG_COMPUTE
}

}  // namespace

extern "C" void kernel_launch(void* const* d_in, const int* in_sizes, int n_in,
                              void* d_out, int out_size, void* d_ws,
                              size_t ws_size, hipStream_t stream) {
  const float* x = (const float*)d_in[0];
  const float* hidden_prev = (const float*)d_in[1];
  const float* Z_state = (const float*)d_in[2];
  const float* F_state = (const float*)d_in[3];
  const float* wz_state = (const float*)d_in[4];
  const float* wf_state = (const float*)d_in[5];
  const float* bz_state = (const float*)d_in[6];
  const float* bf_state = (const float*)d_in[7];
  const float* wm_z = (const float*)d_in[8];
  const float* wm_f = (const float*)d_in[9];
  const float* wv_z = (const float*)d_in[10];
  const float* wv_f = (const float*)d_in[11];
  const float* bias_z = (const float*)d_in[12];
  const float* bias_f = (const float*)d_in[13];

  // Workspace (~59.8 MB):
  float2* pzf = (float2*)d_ws;                 // [SBH] {pre_z,pre_f} -> {zffz,common}
  u16* AzT = (u16*)(pzf + SBH);                // [B*H*S] bf16
  u16* AfT = AzT + SBH;                        // [B*H*S] bf16
  u16* XT = AfT + SBH;                         // [B*D*S] bf16
  u16* wmzb = XT + SBH;                        // [WN]
  u16* wmfb = wmzb + WN;                       // [WN]
  float* P0 = (float*)(wmfb + WN);             // [BH]

  float* out = (float*)d_out;
  float* out_cells = out;                      // S*B*H
  float* out_newcell = out + SBH;              // B*H
  float* out_Zn = out_newcell + BH;            // B*H*D
  float* out_Fn = out_Zn + (size_t)BH * D;     // B*H*D
  float* out_wzn = out_Fn + (size_t)BH * D;    // B*H
  float* out_wfn = out_wzn + BH;
  float* out_bzn = out_wfn + BH;
  float* out_bfn = out_bzn + BH;

  convert_w<<<2 * WN / 8 / 256, 256, 0, stream>>>(wm_z, wm_f, wmzb, wmfb);
  xpose_kernel<<<dim3(S / 64, D / 64, B), 256, 0, stream>>>(x, XT);
  proj_gemm<<<dim3(M1 / 128, H / 64), 256, 0, stream>>>(x, wmzb, wmfb, pzf);
  scan_fwd<<<BH / 64, 64, 0, stream>>>(
      hidden_prev, wz_state, wf_state, bz_state, bf_state, wv_z, wv_f, bias_z,
      bias_f, pzf, out_cells, out_newcell, out_wzn, out_wfn, out_bzn,
      out_bfn);
  suffix_kernel<<<BH / 64, 1024, 0, stream>>>(pzf, AzT, AfT, P0);
  out_gemm<<<dim3(H / 128, D / 64, B), 256, 0, stream>>>(
      AzT, AfT, XT, P0, Z_state, F_state, out_Zn, out_Fn);
}

// Round 9
// 105.500 us; speedup vs baseline: 1.2567x; 1.2567x over previous
//
#include <hip/hip_runtime.h>
#include <math.h>

namespace {

typedef short short8 __attribute__((ext_vector_type(8)));
typedef float floatx4 __attribute__((ext_vector_type(4)));
typedef unsigned int uint32;
typedef unsigned short u16;
typedef unsigned long long u64;

constexpr int S = 256, B = 32, D = 512, H = 512;
constexpr int BH = B * H;        // 16384
constexpr int M1 = S * B;        // 8192
constexpr int WN = H * D;        // 262144
constexpr int SBH = S * BH;      // 4194304 (== B*D*S)

// LDS tiles: rows of exactly 64 bf16 (128B), 16B slot XOR-swizzled by row&7.
__device__ __forceinline__ int swz(int row, int col8) {
  return row * 64 + (col8 ^ ((row & 7) << 3));
}

__device__ __forceinline__ uint32 f2bf(float f) {
  uint32 x = __float_as_uint(f);
  return (x + 0x7fffu + ((x >> 16) & 1u)) >> 16;  // RNE
}

__device__ __forceinline__ float fast_sigmoid(float x) {
  float e = __expf(-x);
  return __builtin_amdgcn_rcpf(1.0f + e);
}
__device__ __forceinline__ float fast_tanh(float x) {
  float e = __expf(-2.0f * x);
  return fmaf(2.0f, __builtin_amdgcn_rcpf(1.0f + e), -1.0f);
}

// ---------------------------------------------------------------------------
// Convert weights to bf16.
// ---------------------------------------------------------------------------
__global__ __launch_bounds__(256) void convert_w(
    const float* __restrict__ wmz, const float* __restrict__ wmf,
    u16* __restrict__ wmzb, u16* __restrict__ wmfb) {
  int i = (blockIdx.x * 256 + threadIdx.x) * 8;
  const float* src;
  u16* dst;
  int off;
  if (i < WN) {
    src = wmz; dst = wmzb; off = i;
  } else {
    src = wmf; dst = wmfb; off = i - WN;
  }
  float4 a = *(const float4*)&src[off];
  float4 b = *(const float4*)&src[off + 4];
  uint4 o;
  o.x = f2bf(a.x) | (f2bf(a.y) << 16);
  o.y = f2bf(a.z) | (f2bf(a.w) << 16);
  o.z = f2bf(b.x) | (f2bf(b.y) << 16);
  o.w = f2bf(b.z) | (f2bf(b.w) << 16);
  *(uint4*)&dst[off] = o;
}

// ---------------------------------------------------------------------------
// Transpose+convert: x (S,B,D) f32  ->  XT [b][d][t] bf16.
// ---------------------------------------------------------------------------
__global__ __launch_bounds__(256) void xpose_kernel(
    const float* __restrict__ x, u16* __restrict__ XT) {
  __shared__ float lds[64][65];
  const int s0 = blockIdx.x * 64;
  const int d0 = blockIdx.y * 64;
  const int b = blockIdx.z;
  const int r = threadIdx.x >> 4;         // 0..15
  const int c4 = (threadIdx.x & 15) * 4;  // 0..60
#pragma unroll
  for (int p = 0; p < 4; ++p) {
    const int rr = r + p * 16;
    float4 v = *(const float4*)&x[(size_t)(s0 + rr) * (B * D) +
                                  (size_t)b * D + d0 + c4];
    lds[c4 + 0][rr] = v.x;
    lds[c4 + 1][rr] = v.y;
    lds[c4 + 2][rr] = v.z;
    lds[c4 + 3][rr] = v.w;
  }
  __syncthreads();
#pragma unroll
  for (int p = 0; p < 4; ++p) {
    const int dr = r + p * 16;
    const float v0 = lds[dr][c4 + 0];
    const float v1 = lds[dr][c4 + 1];
    const float v2 = lds[dr][c4 + 2];
    const float v3 = lds[dr][c4 + 3];
    u64 o = (u64)f2bf(v0) | ((u64)f2bf(v1) << 16) | ((u64)f2bf(v2) << 32) |
            ((u64)f2bf(v3) << 48);
    *(u64*)&XT[((size_t)b * D + d0 + dr) * S + s0 + c4] = o;
  }
}

// ---------------------------------------------------------------------------
// Proj GEMM (MFMA): pre[m][h] = sum_d x[m][d]*wm[h][d], dual-B, out float2.
// BM=128, BN=64, BK=64. Swizzled LDS. x f32->bf16 in-register. (unchanged)
// ---------------------------------------------------------------------------
__global__ __launch_bounds__(256) void proj_gemm(
    const float* __restrict__ x, const u16* __restrict__ wmzb,
    const u16* __restrict__ wmfb, float2* __restrict__ pzf) {
  __shared__ u16 As[128 * 64];
  __shared__ u16 Bzs[64 * 64];
  __shared__ u16 Bfs[64 * 64];
  const int tid = threadIdx.x;
  const int m0 = blockIdx.x * 128;
  const int n0 = blockIdx.y * 64;
  const int w = tid >> 6, l = tid & 63;
  const int lr = l & 15, lg = l >> 4;
  floatx4 accz[2][4], accf[2][4];
#pragma unroll
  for (int m = 0; m < 2; ++m)
#pragma unroll
    for (int n = 0; n < 4; ++n) {
      accz[m][n] = 0;
      accf[m][n] = 0;
    }
  const int sr = tid >> 3;         // 0..31
  const int sc = (tid & 7) * 8;    // 0..56
  for (int k0 = 0; k0 < D; k0 += 64) {
    __syncthreads();
#pragma unroll
    for (int p = 0; p < 4; ++p) {
      const int r = sr + 32 * p;
      const float* xp = &x[(size_t)(m0 + r) * D + k0 + sc];
      float4 a = *(const float4*)xp;
      float4 b = *(const float4*)(xp + 4);
      uint4 o;
      o.x = f2bf(a.x) | (f2bf(a.y) << 16);
      o.y = f2bf(a.z) | (f2bf(a.w) << 16);
      o.z = f2bf(b.x) | (f2bf(b.y) << 16);
      o.w = f2bf(b.z) | (f2bf(b.w) << 16);
      *(uint4*)&As[swz(r, sc)] = o;
    }
#pragma unroll
    for (int p = 0; p < 2; ++p) {
      const int r = sr + 32 * p;
      *(short8*)&Bzs[swz(r, sc)] =
          *(const short8*)&wmzb[(size_t)(n0 + r) * D + k0 + sc];
      *(short8*)&Bfs[swz(r, sc)] =
          *(const short8*)&wmfb[(size_t)(n0 + r) * D + k0 + sc];
    }
    __syncthreads();
#pragma unroll
    for (int kk = 0; kk < 2; ++kk) {
      const int kb = kk * 32 + lg * 8;
      short8 a0 = *(const short8*)&As[swz(32 * w + lr, kb)];
      short8 a1 = *(const short8*)&As[swz(32 * w + 16 + lr, kb)];
#pragma unroll
      for (int n = 0; n < 4; ++n) {
        short8 bz = *(const short8*)&Bzs[swz(16 * n + lr, kb)];
        short8 bf = *(const short8*)&Bfs[swz(16 * n + lr, kb)];
        accz[0][n] = __builtin_amdgcn_mfma_f32_16x16x32_bf16(a0, bz, accz[0][n], 0, 0, 0);
        accz[1][n] = __builtin_amdgcn_mfma_f32_16x16x32_bf16(a1, bz, accz[1][n], 0, 0, 0);
        accf[0][n] = __builtin_amdgcn_mfma_f32_16x16x32_bf16(a0, bf, accf[0][n], 0, 0, 0);
        accf[1][n] = __builtin_amdgcn_mfma_f32_16x16x32_bf16(a1, bf, accf[1][n], 0, 0, 0);
      }
    }
  }
#pragma unroll
  for (int m = 0; m < 2; ++m)
#pragma unroll
    for (int n = 0; n < 4; ++n)
#pragma unroll
      for (int j = 0; j < 4; ++j) {
        int row = m0 + 32 * w + 16 * m + lg * 4 + j;
        int col = n0 + 16 * n + lr;
        pzf[(size_t)row * H + col] = make_float2(accz[m][n][j], accf[m][n][j]);
      }
}

// ---------------------------------------------------------------------------
// Scan forward (unchanged).
// ---------------------------------------------------------------------------
#define STEP_BODY(J)                                                       \
    const float z = fast_tanh(fmaf(wvz, cell, pzv));                       \
    const float f = fast_sigmoid(fmaf(wvf, cell, pfv));                    \
    const float zf = (1.0f - f) * (1.0f - z * z);                          \
    const float fz = (cell - z) * (1.0f - f) * f;                          \
    const float common = f + zf * wvz + fz * wvf;                          \
    wz = fmaf(common, wz, cell * zf);                                      \
    wf = fmaf(common, wf, cell * fz);                                      \
    bz = fmaf(common, bz, zf);                                             \
    bf = fmaf(common, bf, fz);                                             \
    cell = fmaf(f, cell - z, z);                                           \
    const size_t ti = (size_t)(t0 + (J)) * BH;                             \
    cp[ti] = cell;                                                         \
    pz[ti] = make_float2(                                                  \
        __uint_as_float(f2bf(zf) | (f2bf(fz) << 16)), common);

#define STEP_L(J, Q)                                                       \
  {                                                                        \
    const float pzv = Q.x + bsz, pfv = Q.y + bsf;                          \
    Q = pz[(size_t)(t0 + 16 + (J)) * BH];                                  \
    STEP_BODY(J)                                                           \
  }

#define STEP_N(J, Q)                                                       \
  {                                                                        \
    const float pzv = Q.x + bsz, pfv = Q.y + bsf;                          \
    STEP_BODY(J)                                                           \
  }

__global__ __launch_bounds__(64, 1) void scan_fwd(
    const float* __restrict__ hidden_prev, const float* __restrict__ wz0,
    const float* __restrict__ wf0, const float* __restrict__ bz0,
    const float* __restrict__ bf0, const float* __restrict__ wvz_,
    const float* __restrict__ wvf_, const float* __restrict__ bsz_,
    const float* __restrict__ bsf_, float2* pzf_,
    float* __restrict__ out_cells, float* __restrict__ out_newcell,
    float* __restrict__ out_wzn, float* __restrict__ out_wfn,
    float* __restrict__ out_bzn, float* __restrict__ out_bfn) {
  const int bh = blockIdx.x * 64 + threadIdx.x;
  const int h = bh & (H - 1);
  float cell = hidden_prev[bh];
  float wz = wz0[bh], wf = wf0[bh], bz = bz0[bh], bf = bf0[bh];
  const float wvz = wvz_[h], wvf = wvf_[h], bsz = bsz_[h], bsf = bsf_[h];
  float2* pz = pzf_ + bh;
  float* cp = out_cells + bh;

  float2 q0 = pz[(size_t)0 * BH], q1 = pz[(size_t)1 * BH];
  float2 q2 = pz[(size_t)2 * BH], q3 = pz[(size_t)3 * BH];
  float2 q4 = pz[(size_t)4 * BH], q5 = pz[(size_t)5 * BH];
  float2 q6 = pz[(size_t)6 * BH], q7 = pz[(size_t)7 * BH];
  float2 q8 = pz[(size_t)8 * BH], q9 = pz[(size_t)9 * BH];
  float2 q10 = pz[(size_t)10 * BH], q11 = pz[(size_t)11 * BH];
  float2 q12 = pz[(size_t)12 * BH], q13 = pz[(size_t)13 * BH];
  float2 q14 = pz[(size_t)14 * BH], q15 = pz[(size_t)15 * BH];

  for (int t0 = 0; t0 < S - 16; t0 += 16) {
    STEP_L(0, q0)  STEP_L(1, q1)  STEP_L(2, q2)  STEP_L(3, q3)
    STEP_L(4, q4)  STEP_L(5, q5)  STEP_L(6, q6)  STEP_L(7, q7)
    STEP_L(8, q8)  STEP_L(9, q9)  STEP_L(10, q10) STEP_L(11, q11)
    STEP_L(12, q12) STEP_L(13, q13) STEP_L(14, q14) STEP_L(15, q15)
  }
  {
    const int t0 = S - 16;
    STEP_N(0, q0)  STEP_N(1, q1)  STEP_N(2, q2)  STEP_N(3, q3)
    STEP_N(4, q4)  STEP_N(5, q5)  STEP_N(6, q6)  STEP_N(7, q7)
    STEP_N(8, q8)  STEP_N(9, q9)  STEP_N(10, q10) STEP_N(11, q11)
    STEP_N(12, q12) STEP_N(13, q13) STEP_N(14, q14) STEP_N(15, q15)
  }
  out_newcell[bh] = cell;
  out_wzn[bh] = wz;
  out_wfn[bh] = wf;
  out_bzn[bh] = bz;
  out_bfn[bh] = bf;
}

// ---------------------------------------------------------------------------
// Suffix products + transpose to AzT/AfT [b][h][t] bf16. (unchanged)
// ---------------------------------------------------------------------------
__global__ __launch_bounds__(1024) void suffix_kernel(
    const float2* __restrict__ pzfc, u16* __restrict__ AzT,
    u16* __restrict__ AfT, float* __restrict__ P0_out) {
  __shared__ float prods[16][65];
  __shared__ uint32 tl[S * 65];   // [t][bh_l padded]
  const int bh_l = threadIdx.x & 63;
  const int c = threadIdx.x >> 6;
  const int bh = blockIdx.x * 64 + bh_l;
  const float2* p = pzfc + bh;
  float2 v[16];
#pragma unroll
  for (int i = 0; i < 16; ++i) v[i] = p[(size_t)(c * 16 + i) * BH];
  float L = 1.0f;
#pragma unroll
  for (int i = 0; i < 16; ++i) L *= v[i].y;
  prods[c][bh_l] = L;
  __syncthreads();
  float run = 1.0f;
#pragma unroll
  for (int cc = 1; cc < 16; ++cc)
    if (cc > c) run *= prods[cc][bh_l];
#pragma unroll
  for (int i = 15; i >= 0; --i) {
    const int t = c * 16 + i;
    const uint32 w32 = __float_as_uint(v[i].x);
    const float zf = __uint_as_float((w32 & 0xffffu) << 16);
    const float fz = __uint_as_float(w32 & 0xffff0000u);
    tl[t * 65 + bh_l] = f2bf(zf * run) | (f2bf(fz * run) << 16);
    run *= v[i].y;
  }
  if (c == 0) P0_out[bh] = run;
  __syncthreads();
  const size_t base = (size_t)blockIdx.x * 64 * S;
#pragma unroll
  for (int it = 0; it < 4; ++it) {
    const int qi = it * 1024 + threadIdx.x;  // 4096 quads
    const int r = qi >> 6;                   // chain row 0..63
    const int qt = (qi & 63) * 4;            // t 0..252
    const uint32 a0 = tl[(qt + 0) * 65 + r];
    const uint32 a1 = tl[(qt + 1) * 65 + r];
    const uint32 a2 = tl[(qt + 2) * 65 + r];
    const uint32 a3 = tl[(qt + 3) * 65 + r];
    u64 lo = (u64)(a0 & 0xffffu) | ((u64)(a1 & 0xffffu) << 16) |
             ((u64)(a2 & 0xffffu) << 32) | ((u64)(a3 & 0xffffu) << 48);
    u64 hi = (u64)(a0 >> 16) | ((u64)(a1 >> 16) << 16) |
             ((u64)(a2 >> 16) << 32) | ((u64)(a3 >> 16) << 48);
    *(u64*)&AzT[base + (size_t)r * S + qt] = lo;
    *(u64*)&AfT[base + (size_t)r * S + qt] = hi;
  }
}

// ---------------------------------------------------------------------------
// Out GEMM, round 9: Z and F handled by SEPARATE blocks (grid z = B*2).
//   Cn[b][h][d] = p0*C0 + sum_t A[b][h][t]*XT[b][d][t]
// BM=128(h), BN=64(d), BK=64(t). Reg-staged double-buffered LDS (r7's proven
// pipeline), 24KB/buffer -> 48KB -> 3 blocks/CU with __launch_bounds__(256,3)
// (VGPR cap 170 >> need ~110; r8's (256,4) cap of 128 made regalloc emit 64
// regs + scratch spill). Epilogue: acc staged through LDS (f32, pad-68 rows,
// reuses tile memory) so all C0/Cn traffic is float4 (G13).
// ---------------------------------------------------------------------------
__global__ __launch_bounds__(256, 3) void out_gemm(
    const u16* __restrict__ AzT, const u16* __restrict__ AfT,
    const u16* __restrict__ XT, const float* __restrict__ P0,
    const float* __restrict__ Z0, const float* __restrict__ F0,
    float* __restrict__ Zn, float* __restrict__ Fn) {
  __shared__ u16 smem[2][(128 + 64) * 64];   // per buffer: A 128x64 | X 64x64
  const int tid = threadIdx.x;
  const int h0 = blockIdx.x * 128;
  const int d0 = blockIdx.y * 64;
  const int bz = blockIdx.z;
  const int b = bz >> 1;
  const u16* A = ((bz & 1) ? AfT : AzT) + (size_t)b * H * S;
  const float* C0 = (bz & 1) ? F0 : Z0;
  float* Cn = (bz & 1) ? Fn : Zn;
  const u16* Xb = XT + (size_t)b * D * S;
  const int w = tid >> 6, l = tid & 63;
  const int lr = l & 15, lg = l >> 4;
  floatx4 acc[2][4];
#pragma unroll
  for (int m = 0; m < 2; ++m)
#pragma unroll
    for (int n = 0; n < 4; ++n) acc[m][n] = 0;
  const int sr = tid >> 3;         // 0..31
  const int sc = (tid & 7) * 8;    // 0..56

  short8 rA[4], rX[2];

#define OG_LOAD(T0)                                                        \
  {                                                                        \
    _Pragma("unroll") for (int p = 0; p < 4; ++p) {                        \
      const int r = sr + 32 * p;                                           \
      rA[p] = *(const short8*)&A[(size_t)(h0 + r) * S + (T0) + sc];        \
    }                                                                      \
    _Pragma("unroll") for (int p = 0; p < 2; ++p) {                        \
      const int r = sr + 32 * p;                                           \
      rX[p] = *(const short8*)&Xb[(size_t)(d0 + r) * S + (T0) + sc];       \
    }                                                                      \
  }

#define OG_WRITE(BUF)                                                      \
  {                                                                        \
    u16* As_ = smem[BUF];                                                  \
    u16* Xs_ = smem[BUF] + 128 * 64;                                       \
    _Pragma("unroll") for (int p = 0; p < 4; ++p) {                        \
      const int r = sr + 32 * p;                                           \
      *(short8*)&As_[swz(r, sc)] = rA[p];                                  \
    }                                                                      \
    _Pragma("unroll") for (int p = 0; p < 2; ++p) {                        \
      const int r = sr + 32 * p;                                           \
      *(short8*)&Xs_[swz(r, sc)] = rX[p];                                  \
    }                                                                      \
  }

#define OG_COMPUTE(BUF)                                                    \
  {                                                                        \
    const u16* As_ = smem[BUF];                                            \
    const u16* Xs_ = smem[BUF] + 128 * 64;                                 \
    _Pragma("unroll") for (int kk = 0; kk < 2; ++kk) {                     \
      const int kb = kk * 32 + lg * 8;                                     \
      short8 a0 = *(const short8*)&As_[swz(32 * w + lr, kb)];              \
      short8 a1 = *(const short8*)&As_[swz(32 * w + 16 + lr, kb)];         \
      _Pragma("unroll") for (int n = 0; n < 4; ++n) {                      \
        short8 xf = *(const short8*)&Xs_[swz(16 * n + lr, kb)];            \
        acc[0][n] = __builtin_amdgcn_mfma_f32_16x16x32_bf16(a0, xf, acc[0][n], 0, 0, 0); \
        acc[1][n] = __builtin_amdgcn_mfma_f32_16x16x32_bf16(a1, xf, acc[1][n], 0, 0, 0); \
      }                                                                    \
    }                                                                      \
  }

  OG_LOAD(0)
  OG_WRITE(0)
  __syncthreads();
  OG_LOAD(64)
  OG_COMPUTE(0)
  OG_WRITE(1)
  __syncthreads();
  OG_LOAD(128)
  OG_COMPUTE(1)
  OG_WRITE(0)
  __syncthreads();
  OG_LOAD(192)
  OG_COMPUTE(0)
  OG_WRITE(1)
  __syncthreads();
  OG_COMPUTE(1)

  // ---- epilogue: acc -> LDS (f32) -> float4 global IO ----
  __syncthreads();                       // all LDS reads of buf1 done
  float* eps = (float*)&smem[0][0];      // 128 rows x pad 68 f32 = 33.3KB
#pragma unroll
  for (int m = 0; m < 2; ++m)
#pragma unroll
    for (int n = 0; n < 4; ++n)
#pragma unroll
      for (int j = 0; j < 4; ++j) {
        const int row = 32 * w + 16 * m + lg * 4 + j;
        eps[row * 68 + 16 * n + lr] = acc[m][n][j];
      }
  __syncthreads();
#pragma unroll
  for (int i = 0; i < 8; ++i) {
    const int id = i * 256 + tid;
    const int row = id >> 4;             // 0..127
    const int c4 = (id & 15) * 4;        // 0..60
    const int h = h0 + row;
    const float p0 = P0[b * H + h];
    const size_t gi = ((size_t)b * H + h) * D + d0 + c4;
    const float4 a = *(const float4*)&eps[row * 68 + c4];
    const float4 c0 = *(const float4*)&C0[gi];
    float4 o;
    o.x = fmaf(p0, c0.x, a.x);
    o.y = fmaf(p0, c0.y, a.y);
    o.z = fmaf(p0, c0.z, a.z);
    o.w = fmaf(p0, c0.w, a.w);
    *(float4*)&Cn[gi] = o;
  }
#undef OG_LOAD
#undef OG_WRITE
#undef OG_COMPUTE
}

}  // namespace

extern "C" void kernel_launch(void* const* d_in, const int* in_sizes, int n_in,
                              void* d_out, int out_size, void* d_ws,
                              size_t ws_size, hipStream_t stream) {
  const float* x = (const float*)d_in[0];
  const float* hidden_prev = (const float*)d_in[1];
  const float* Z_state = (const float*)d_in[2];
  const float* F_state = (const float*)d_in[3];
  const float* wz_state = (const float*)d_in[4];
  const float* wf_state = (const float*)d_in[5];
  const float* bz_state = (const float*)d_in[6];
  const float* bf_state = (const float*)d_in[7];
  const float* wm_z = (const float*)d_in[8];
  const float* wm_f = (const float*)d_in[9];
  const float* wv_z = (const float*)d_in[10];
  const float* wv_f = (const float*)d_in[11];
  const float* bias_z = (const float*)d_in[12];
  const float* bias_f = (const float*)d_in[13];

  // Workspace (~59.8 MB):
  float2* pzf = (float2*)d_ws;                 // [SBH] {pre_z,pre_f} -> {zffz,common}
  u16* AzT = (u16*)(pzf + SBH);                // [B*H*S] bf16
  u16* AfT = AzT + SBH;                        // [B*H*S] bf16
  u16* XT = AfT + SBH;                         // [B*D*S] bf16
  u16* wmzb = XT + SBH;                        // [WN]
  u16* wmfb = wmzb + WN;                       // [WN]
  float* P0 = (float*)(wmfb + WN);             // [BH]

  float* out = (float*)d_out;
  float* out_cells = out;                      // S*B*H
  float* out_newcell = out + SBH;              // B*H
  float* out_Zn = out_newcell + BH;            // B*H*D
  float* out_Fn = out_Zn + (size_t)BH * D;     // B*H*D
  float* out_wzn = out_Fn + (size_t)BH * D;    // B*H
  float* out_wfn = out_wzn + BH;
  float* out_bzn = out_wfn + BH;
  float* out_bfn = out_bzn + BH;

  convert_w<<<2 * WN / 8 / 256, 256, 0, stream>>>(wm_z, wm_f, wmzb, wmfb);
  xpose_kernel<<<dim3(S / 64, D / 64, B), 256, 0, stream>>>(x, XT);
  proj_gemm<<<dim3(M1 / 128, H / 64), 256, 0, stream>>>(x, wmzb, wmfb, pzf);
  scan_fwd<<<BH / 64, 64, 0, stream>>>(
      hidden_prev, wz_state, wf_state, bz_state, bf_state, wv_z, wv_f, bias_z,
      bias_f, pzf, out_cells, out_newcell, out_wzn, out_wfn, out_bzn,
      out_bfn);
  suffix_kernel<<<BH / 64, 1024, 0, stream>>>(pzf, AzT, AfT, P0);
  out_gemm<<<dim3(H / 128, D / 64, B * 2), 256, 0, stream>>>(
      AzT, AfT, XT, P0, Z_state, F_state, out_Zn, out_Fn);
}

// Round 10
// 101.887 us; speedup vs baseline: 1.3012x; 1.0355x over previous
//
#include <hip/hip_runtime.h>
#include <math.h>

namespace {

typedef short short8 __attribute__((ext_vector_type(8)));
typedef float floatx4 __attribute__((ext_vector_type(4)));
typedef unsigned int uint32;
typedef unsigned short u16;
typedef unsigned long long u64;

constexpr int S = 256, B = 32, D = 512, H = 512;
constexpr int BH = B * H;        // 16384
constexpr int M1 = S * B;        // 8192
constexpr int WN = H * D;        // 262144
constexpr int SBH = S * BH;      // 4194304 (== B*D*S)

// LDS tiles: rows of exactly 64 bf16 (128B), 16B slot XOR-swizzled by row&7.
__device__ __forceinline__ int swz(int row, int col8) {
  return row * 64 + (col8 ^ ((row & 7) << 3));
}

__device__ __forceinline__ uint32 f2bf(float f) {
  uint32 x = __float_as_uint(f);
  return (x + 0x7fffu + ((x >> 16) & 1u)) >> 16;  // RNE
}

__device__ __forceinline__ float fast_sigmoid(float x) {
  float e = __expf(-x);
  return __builtin_amdgcn_rcpf(1.0f + e);
}
__device__ __forceinline__ float fast_tanh(float x) {
  float e = __expf(-2.0f * x);
  return fmaf(2.0f, __builtin_amdgcn_rcpf(1.0f + e), -1.0f);
}

// ---------------------------------------------------------------------------
// Fused prep: blocks [0,1024) transpose+convert x -> XT [b][d][t] bf16;
// blocks [1024,1280) convert weights to bf16. One launch instead of two.
// ---------------------------------------------------------------------------
__global__ __launch_bounds__(256) void prep_kernel(
    const float* __restrict__ x, const float* __restrict__ wmz,
    const float* __restrict__ wmf, u16* __restrict__ XT,
    u16* __restrict__ wmzb, u16* __restrict__ wmfb) {
  __shared__ float lds[64][65];
  const int bid = blockIdx.x;
  if (bid < 1024) {
    const int b = bid >> 5;
    const int rem = bid & 31;
    const int d0 = (rem >> 2) * 64;
    const int s0 = (rem & 3) * 64;
    const int r = threadIdx.x >> 4;         // 0..15
    const int c4 = (threadIdx.x & 15) * 4;  // 0..60
#pragma unroll
    for (int p = 0; p < 4; ++p) {
      const int rr = r + p * 16;
      float4 v = *(const float4*)&x[(size_t)(s0 + rr) * (B * D) +
                                    (size_t)b * D + d0 + c4];
      lds[c4 + 0][rr] = v.x;
      lds[c4 + 1][rr] = v.y;
      lds[c4 + 2][rr] = v.z;
      lds[c4 + 3][rr] = v.w;
    }
    __syncthreads();
#pragma unroll
    for (int p = 0; p < 4; ++p) {
      const int dr = r + p * 16;
      const float v0 = lds[dr][c4 + 0];
      const float v1 = lds[dr][c4 + 1];
      const float v2 = lds[dr][c4 + 2];
      const float v3 = lds[dr][c4 + 3];
      u64 o = (u64)f2bf(v0) | ((u64)f2bf(v1) << 16) | ((u64)f2bf(v2) << 32) |
              ((u64)f2bf(v3) << 48);
      *(u64*)&XT[((size_t)b * D + d0 + dr) * S + s0 + c4] = o;
    }
  } else {
    int i = ((bid - 1024) * 256 + threadIdx.x) * 8;
    const float* src;
    u16* dst;
    int off;
    if (i < WN) {
      src = wmz; dst = wmzb; off = i;
    } else {
      src = wmf; dst = wmfb; off = i - WN;
    }
    float4 a = *(const float4*)&src[off];
    float4 b4 = *(const float4*)&src[off + 4];
    uint4 o;
    o.x = f2bf(a.x) | (f2bf(a.y) << 16);
    o.y = f2bf(a.z) | (f2bf(a.w) << 16);
    o.z = f2bf(b4.x) | (f2bf(b4.y) << 16);
    o.w = f2bf(b4.z) | (f2bf(b4.w) << 16);
    *(uint4*)&dst[off] = o;
  }
}

// ---------------------------------------------------------------------------
// Proj GEMM (MFMA): pre[m][h] = sum_d x[m][d]*wm[h][d], dual-B, out float2.
// BM=128, BN=64, BK=64. Swizzled LDS. x f32->bf16 in-register. (unchanged)
// ---------------------------------------------------------------------------
__global__ __launch_bounds__(256) void proj_gemm(
    const float* __restrict__ x, const u16* __restrict__ wmzb,
    const u16* __restrict__ wmfb, float2* __restrict__ pzf) {
  __shared__ u16 As[128 * 64];
  __shared__ u16 Bzs[64 * 64];
  __shared__ u16 Bfs[64 * 64];
  const int tid = threadIdx.x;
  const int m0 = blockIdx.x * 128;
  const int n0 = blockIdx.y * 64;
  const int w = tid >> 6, l = tid & 63;
  const int lr = l & 15, lg = l >> 4;
  floatx4 accz[2][4], accf[2][4];
#pragma unroll
  for (int m = 0; m < 2; ++m)
#pragma unroll
    for (int n = 0; n < 4; ++n) {
      accz[m][n] = 0;
      accf[m][n] = 0;
    }
  const int sr = tid >> 3;         // 0..31
  const int sc = (tid & 7) * 8;    // 0..56
  for (int k0 = 0; k0 < D; k0 += 64) {
    __syncthreads();
#pragma unroll
    for (int p = 0; p < 4; ++p) {
      const int r = sr + 32 * p;
      const float* xp = &x[(size_t)(m0 + r) * D + k0 + sc];
      float4 a = *(const float4*)xp;
      float4 b = *(const float4*)(xp + 4);
      uint4 o;
      o.x = f2bf(a.x) | (f2bf(a.y) << 16);
      o.y = f2bf(a.z) | (f2bf(a.w) << 16);
      o.z = f2bf(b.x) | (f2bf(b.y) << 16);
      o.w = f2bf(b.z) | (f2bf(b.w) << 16);
      *(uint4*)&As[swz(r, sc)] = o;
    }
#pragma unroll
    for (int p = 0; p < 2; ++p) {
      const int r = sr + 32 * p;
      *(short8*)&Bzs[swz(r, sc)] =
          *(const short8*)&wmzb[(size_t)(n0 + r) * D + k0 + sc];
      *(short8*)&Bfs[swz(r, sc)] =
          *(const short8*)&wmfb[(size_t)(n0 + r) * D + k0 + sc];
    }
    __syncthreads();
    __builtin_amdgcn_s_setprio(1);
#pragma unroll
    for (int kk = 0; kk < 2; ++kk) {
      const int kb = kk * 32 + lg * 8;
      short8 a0 = *(const short8*)&As[swz(32 * w + lr, kb)];
      short8 a1 = *(const short8*)&As[swz(32 * w + 16 + lr, kb)];
#pragma unroll
      for (int n = 0; n < 4; ++n) {
        short8 bz = *(const short8*)&Bzs[swz(16 * n + lr, kb)];
        short8 bf = *(const short8*)&Bfs[swz(16 * n + lr, kb)];
        accz[0][n] = __builtin_amdgcn_mfma_f32_16x16x32_bf16(a0, bz, accz[0][n], 0, 0, 0);
        accz[1][n] = __builtin_amdgcn_mfma_f32_16x16x32_bf16(a1, bz, accz[1][n], 0, 0, 0);
        accf[0][n] = __builtin_amdgcn_mfma_f32_16x16x32_bf16(a0, bf, accf[0][n], 0, 0, 0);
        accf[1][n] = __builtin_amdgcn_mfma_f32_16x16x32_bf16(a1, bf, accf[1][n], 0, 0, 0);
      }
    }
    __builtin_amdgcn_s_setprio(0);
  }
#pragma unroll
  for (int m = 0; m < 2; ++m)
#pragma unroll
    for (int n = 0; n < 4; ++n)
#pragma unroll
      for (int j = 0; j < 4; ++j) {
        int row = m0 + 32 * w + 16 * m + lg * 4 + j;
        int col = n0 + 16 * n + lr;
        pzf[(size_t)row * H + col] = make_float2(accz[m][n][j], accf[m][n][j]);
      }
}

// ---------------------------------------------------------------------------
// Scan forward (unchanged).
// ---------------------------------------------------------------------------
#define STEP_BODY(J)                                                       \
    const float z = fast_tanh(fmaf(wvz, cell, pzv));                       \
    const float f = fast_sigmoid(fmaf(wvf, cell, pfv));                    \
    const float zf = (1.0f - f) * (1.0f - z * z);                          \
    const float fz = (cell - z) * (1.0f - f) * f;                          \
    const float common = f + zf * wvz + fz * wvf;                          \
    wz = fmaf(common, wz, cell * zf);                                      \
    wf = fmaf(common, wf, cell * fz);                                      \
    bz = fmaf(common, bz, zf);                                             \
    bf = fmaf(common, bf, fz);                                             \
    cell = fmaf(f, cell - z, z);                                           \
    const size_t ti = (size_t)(t0 + (J)) * BH;                             \
    cp[ti] = cell;                                                         \
    pz[ti] = make_float2(                                                  \
        __uint_as_float(f2bf(zf) | (f2bf(fz) << 16)), common);

#define STEP_L(J, Q)                                                       \
  {                                                                        \
    const float pzv = Q.x + bsz, pfv = Q.y + bsf;                          \
    Q = pz[(size_t)(t0 + 16 + (J)) * BH];                                  \
    STEP_BODY(J)                                                           \
  }

#define STEP_N(J, Q)                                                       \
  {                                                                        \
    const float pzv = Q.x + bsz, pfv = Q.y + bsf;                          \
    STEP_BODY(J)                                                           \
  }

__global__ __launch_bounds__(64, 1) void scan_fwd(
    const float* __restrict__ hidden_prev, const float* __restrict__ wz0,
    const float* __restrict__ wf0, const float* __restrict__ bz0,
    const float* __restrict__ bf0, const float* __restrict__ wvz_,
    const float* __restrict__ wvf_, const float* __restrict__ bsz_,
    const float* __restrict__ bsf_, float2* pzf_,
    float* __restrict__ out_cells, float* __restrict__ out_newcell,
    float* __restrict__ out_wzn, float* __restrict__ out_wfn,
    float* __restrict__ out_bzn, float* __restrict__ out_bfn) {
  const int bh = blockIdx.x * 64 + threadIdx.x;
  const int h = bh & (H - 1);
  float cell = hidden_prev[bh];
  float wz = wz0[bh], wf = wf0[bh], bz = bz0[bh], bf = bf0[bh];
  const float wvz = wvz_[h], wvf = wvf_[h], bsz = bsz_[h], bsf = bsf_[h];
  float2* pz = pzf_ + bh;
  float* cp = out_cells + bh;

  float2 q0 = pz[(size_t)0 * BH], q1 = pz[(size_t)1 * BH];
  float2 q2 = pz[(size_t)2 * BH], q3 = pz[(size_t)3 * BH];
  float2 q4 = pz[(size_t)4 * BH], q5 = pz[(size_t)5 * BH];
  float2 q6 = pz[(size_t)6 * BH], q7 = pz[(size_t)7 * BH];
  float2 q8 = pz[(size_t)8 * BH], q9 = pz[(size_t)9 * BH];
  float2 q10 = pz[(size_t)10 * BH], q11 = pz[(size_t)11 * BH];
  float2 q12 = pz[(size_t)12 * BH], q13 = pz[(size_t)13 * BH];
  float2 q14 = pz[(size_t)14 * BH], q15 = pz[(size_t)15 * BH];

  for (int t0 = 0; t0 < S - 16; t0 += 16) {
    STEP_L(0, q0)  STEP_L(1, q1)  STEP_L(2, q2)  STEP_L(3, q3)
    STEP_L(4, q4)  STEP_L(5, q5)  STEP_L(6, q6)  STEP_L(7, q7)
    STEP_L(8, q8)  STEP_L(9, q9)  STEP_L(10, q10) STEP_L(11, q11)
    STEP_L(12, q12) STEP_L(13, q13) STEP_L(14, q14) STEP_L(15, q15)
  }
  {
    const int t0 = S - 16;
    STEP_N(0, q0)  STEP_N(1, q1)  STEP_N(2, q2)  STEP_N(3, q3)
    STEP_N(4, q4)  STEP_N(5, q5)  STEP_N(6, q6)  STEP_N(7, q7)
    STEP_N(8, q8)  STEP_N(9, q9)  STEP_N(10, q10) STEP_N(11, q11)
    STEP_N(12, q12) STEP_N(13, q13) STEP_N(14, q14) STEP_N(15, q15)
  }
  out_newcell[bh] = cell;
  out_wzn[bh] = wz;
  out_wfn[bh] = wf;
  out_bzn[bh] = bz;
  out_bfn[bh] = bf;
}

// ---------------------------------------------------------------------------
// Suffix products + transpose to AzT/AfT [b][h][t] bf16. (unchanged)
// ---------------------------------------------------------------------------
__global__ __launch_bounds__(1024) void suffix_kernel(
    const float2* __restrict__ pzfc, u16* __restrict__ AzT,
    u16* __restrict__ AfT, float* __restrict__ P0_out) {
  __shared__ float prods[16][65];
  __shared__ uint32 tl[S * 65];   // [t][bh_l padded]
  const int bh_l = threadIdx.x & 63;
  const int c = threadIdx.x >> 6;
  const int bh = blockIdx.x * 64 + bh_l;
  const float2* p = pzfc + bh;
  float2 v[16];
#pragma unroll
  for (int i = 0; i < 16; ++i) v[i] = p[(size_t)(c * 16 + i) * BH];
  float L = 1.0f;
#pragma unroll
  for (int i = 0; i < 16; ++i) L *= v[i].y;
  prods[c][bh_l] = L;
  __syncthreads();
  float run = 1.0f;
#pragma unroll
  for (int cc = 1; cc < 16; ++cc)
    if (cc > c) run *= prods[cc][bh_l];
#pragma unroll
  for (int i = 15; i >= 0; --i) {
    const int t = c * 16 + i;
    const uint32 w32 = __float_as_uint(v[i].x);
    const float zf = __uint_as_float((w32 & 0xffffu) << 16);
    const float fz = __uint_as_float(w32 & 0xffff0000u);
    tl[t * 65 + bh_l] = f2bf(zf * run) | (f2bf(fz * run) << 16);
    run *= v[i].y;
  }
  if (c == 0) P0_out[bh] = run;
  __syncthreads();
  const size_t base = (size_t)blockIdx.x * 64 * S;
#pragma unroll
  for (int it = 0; it < 4; ++it) {
    const int qi = it * 1024 + threadIdx.x;  // 4096 quads
    const int r = qi >> 6;                   // chain row 0..63
    const int qt = (qi & 63) * 4;            // t 0..252
    const uint32 a0 = tl[(qt + 0) * 65 + r];
    const uint32 a1 = tl[(qt + 1) * 65 + r];
    const uint32 a2 = tl[(qt + 2) * 65 + r];
    const uint32 a3 = tl[(qt + 3) * 65 + r];
    u64 lo = (u64)(a0 & 0xffffu) | ((u64)(a1 & 0xffffu) << 16) |
             ((u64)(a2 & 0xffffu) << 32) | ((u64)(a3 & 0xffffu) << 48);
    u64 hi = (u64)(a0 >> 16) | ((u64)(a1 >> 16) << 16) |
             ((u64)(a2 >> 16) << 32) | ((u64)(a3 >> 16) << 48);
    *(u64*)&AzT[base + (size_t)r * S + qt] = lo;
    *(u64*)&AfT[base + (size_t)r * S + qt] = hi;
  }
}

// ---------------------------------------------------------------------------
// Out GEMM, round 10: r9 structure (Z/F split blocks, dbuf reg-staged,
// (256,3)) + epilogue C0/P0 prefetch issued BEFORE the final COMPUTE (their
// ~500cy latency hides under MFMA + LDS transpose) + setprio around MFMA
// (3 blocks/CU -> cross-block role diversity).
// ---------------------------------------------------------------------------
__global__ __launch_bounds__(256, 3) void out_gemm(
    const u16* __restrict__ AzT, const u16* __restrict__ AfT,
    const u16* __restrict__ XT, const float* __restrict__ P0,
    const float* __restrict__ Z0, const float* __restrict__ F0,
    float* __restrict__ Zn, float* __restrict__ Fn) {
  __shared__ u16 smem[2][(128 + 64) * 64];   // per buffer: A 128x64 | X 64x64
  const int tid = threadIdx.x;
  const int h0 = blockIdx.x * 128;
  const int d0 = blockIdx.y * 64;
  const int bz = blockIdx.z;
  const int b = bz >> 1;
  const u16* A = ((bz & 1) ? AfT : AzT) + (size_t)b * H * S;
  const float* C0 = (bz & 1) ? F0 : Z0;
  float* Cn = (bz & 1) ? Fn : Zn;
  const u16* Xb = XT + (size_t)b * D * S;
  const int w = tid >> 6, l = tid & 63;
  const int lr = l & 15, lg = l >> 4;
  floatx4 acc[2][4];
#pragma unroll
  for (int m = 0; m < 2; ++m)
#pragma unroll
    for (int n = 0; n < 4; ++n) acc[m][n] = 0;
  const int sr = tid >> 3;         // 0..31
  const int sc = (tid & 7) * 8;    // 0..56

  short8 rA[4], rX[2];

#define OG_LOAD(T0)                                                        \
  {                                                                        \
    _Pragma("unroll") for (int p = 0; p < 4; ++p) {                        \
      const int r = sr + 32 * p;                                           \
      rA[p] = *(const short8*)&A[(size_t)(h0 + r) * S + (T0) + sc];        \
    }                                                                      \
    _Pragma("unroll") for (int p = 0; p < 2; ++p) {                        \
      const int r = sr + 32 * p;                                           \
      rX[p] = *(const short8*)&Xb[(size_t)(d0 + r) * S + (T0) + sc];       \
    }                                                                      \
  }

#define OG_WRITE(BUF)                                                      \
  {                                                                        \
    u16* As_ = smem[BUF];                                                  \
    u16* Xs_ = smem[BUF] + 128 * 64;                                       \
    _Pragma("unroll") for (int p = 0; p < 4; ++p) {                        \
      const int r = sr + 32 * p;                                           \
      *(short8*)&As_[swz(r, sc)] = rA[p];                                  \
    }                                                                      \
    _Pragma("unroll") for (int p = 0; p < 2; ++p) {                        \
      const int r = sr + 32 * p;                                           \
      *(short8*)&Xs_[swz(r, sc)] = rX[p];                                  \
    }                                                                      \
  }

#define OG_COMPUTE(BUF)                                                    \
  {                                                                        \
    const u16* As_ = smem[BUF];                                            \
    const u16* Xs_ = smem[BUF] + 128 * 64;                                 \
    __builtin_amdgcn_s_setprio(1);                                         \
    _Pragma("unroll") for (int kk = 0; kk < 2; ++kk) {                     \
      const int kb = kk * 32 + lg * 8;                                     \
      short8 a0 = *(const short8*)&As_[swz(32 * w + lr, kb)];              \
      short8 a1 = *(const short8*)&As_[swz(32 * w + 16 + lr, kb)];         \
      _Pragma("unroll") for (int n = 0; n < 4; ++n) {                      \
        short8 xf = *(const short8*)&Xs_[swz(16 * n + lr, kb)];            \
        acc[0][n] = __builtin_amdgcn_mfma_f32_16x16x32_bf16(a0, xf, acc[0][n], 0, 0, 0); \
        acc[1][n] = __builtin_amdgcn_mfma_f32_16x16x32_bf16(a1, xf, acc[1][n], 0, 0, 0); \
      }                                                                    \
    }                                                                      \
    __builtin_amdgcn_s_setprio(0);                                         \
  }

  OG_LOAD(0)
  OG_WRITE(0)
  __syncthreads();
  OG_LOAD(64)
  OG_COMPUTE(0)
  OG_WRITE(1)
  __syncthreads();
  OG_LOAD(128)
  OG_COMPUTE(1)
  OG_WRITE(0)
  __syncthreads();
  OG_LOAD(192)
  OG_COMPUTE(0)
  OG_WRITE(1)
  __syncthreads();

  // Epilogue prefetch BEFORE the last compute: C0 float4s + P0 scalars for
  // this thread's 8 output quads. Latency hides under COMPUTE(1) + the LDS
  // transpose below.
  float4 c0v[8];
  float p0v[8];
#pragma unroll
  for (int i = 0; i < 8; ++i) {
    const int id = i * 256 + tid;
    const int row = id >> 4;             // 0..127
    const int c4 = (id & 15) * 4;        // 0..60
    const int h = h0 + row;
    p0v[i] = P0[b * H + h];
    c0v[i] = *(const float4*)&C0[((size_t)b * H + h) * D + d0 + c4];
  }

  OG_COMPUTE(1)

  // ---- epilogue: acc -> LDS (f32) -> float4 combine/store ----
  __syncthreads();                       // all LDS reads of buf1 done
  float* eps = (float*)&smem[0][0];      // 128 rows x pad 68 f32 = 33.3KB
#pragma unroll
  for (int m = 0; m < 2; ++m)
#pragma unroll
    for (int n = 0; n < 4; ++n)
#pragma unroll
      for (int j = 0; j < 4; ++j) {
        const int row = 32 * w + 16 * m + lg * 4 + j;
        eps[row * 68 + 16 * n + lr] = acc[m][n][j];
      }
  __syncthreads();
#pragma unroll
  for (int i = 0; i < 8; ++i) {
    const int id = i * 256 + tid;
    const int row = id >> 4;             // 0..127
    const int c4 = (id & 15) * 4;        // 0..60
    const int h = h0 + row;
    const size_t gi = ((size_t)b * H + h) * D + d0 + c4;
    const float4 a = *(const float4*)&eps[row * 68 + c4];
    float4 o;
    o.x = fmaf(p0v[i], c0v[i].x, a.x);
    o.y = fmaf(p0v[i], c0v[i].y, a.y);
    o.z = fmaf(p0v[i], c0v[i].z, a.z);
    o.w = fmaf(p0v[i], c0v[i].w, a.w);
    *(float4*)&Cn[gi] = o;
  }
#undef OG_LOAD
#undef OG_WRITE
#undef OG_COMPUTE
}

}  // namespace

extern "C" void kernel_launch(void* const* d_in, const int* in_sizes, int n_in,
                              void* d_out, int out_size, void* d_ws,
                              size_t ws_size, hipStream_t stream) {
  const float* x = (const float*)d_in[0];
  const float* hidden_prev = (const float*)d_in[1];
  const float* Z_state = (const float*)d_in[2];
  const float* F_state = (const float*)d_in[3];
  const float* wz_state = (const float*)d_in[4];
  const float* wf_state = (const float*)d_in[5];
  const float* bz_state = (const float*)d_in[6];
  const float* bf_state = (const float*)d_in[7];
  const float* wm_z = (const float*)d_in[8];
  const float* wm_f = (const float*)d_in[9];
  const float* wv_z = (const float*)d_in[10];
  const float* wv_f = (const float*)d_in[11];
  const float* bias_z = (const float*)d_in[12];
  const float* bias_f = (const float*)d_in[13];

  // Workspace (~59.8 MB):
  float2* pzf = (float2*)d_ws;                 // [SBH] {pre_z,pre_f} -> {zffz,common}
  u16* AzT = (u16*)(pzf + SBH);                // [B*H*S] bf16
  u16* AfT = AzT + SBH;                        // [B*H*S] bf16
  u16* XT = AfT + SBH;                         // [B*D*S] bf16
  u16* wmzb = XT + SBH;                        // [WN]
  u16* wmfb = wmzb + WN;                       // [WN]
  float* P0 = (float*)(wmfb + WN);             // [BH]

  float* out = (float*)d_out;
  float* out_cells = out;                      // S*B*H
  float* out_newcell = out + SBH;              // B*H
  float* out_Zn = out_newcell + BH;            // B*H*D
  float* out_Fn = out_Zn + (size_t)BH * D;     // B*H*D
  float* out_wzn = out_Fn + (size_t)BH * D;    // B*H
  float* out_wfn = out_wzn + BH;
  float* out_bzn = out_wfn + BH;
  float* out_bfn = out_bzn + BH;

  prep_kernel<<<1024 + 256, 256, 0, stream>>>(x, wm_z, wm_f, XT, wmzb, wmfb);
  proj_gemm<<<dim3(M1 / 128, H / 64), 256, 0, stream>>>(x, wmzb, wmfb, pzf);
  scan_fwd<<<BH / 64, 64, 0, stream>>>(
      hidden_prev, wz_state, wf_state, bz_state, bf_state, wv_z, wv_f, bias_z,
      bias_f, pzf, out_cells, out_newcell, out_wzn, out_wfn, out_bzn,
      out_bfn);
  suffix_kernel<<<BH / 64, 1024, 0, stream>>>(pzf, AzT, AfT, P0);
  out_gemm<<<dim3(H / 128, D / 64, B * 2), 256, 0, stream>>>(
      AzT, AfT, XT, P0, Z_state, F_state, out_Zn, out_Fn);
}